// Round 1
// 502.139 us; speedup vs baseline: 1.0608x; 1.0608x over previous
//
#include <hip/hip_runtime.h>
#include <cstdint>
#include <cstddef>

#define K_DIM 4096
#define N_DIM 4096
#define BM 256
#define BN 256
#define BK 64            // K-step; LDS row = 128 B = full bank period
#define NT (K_DIM / BK)  // 64 K-tiles

typedef __attribute__((ext_vector_type(8))) short short8;
typedef __attribute__((ext_vector_type(4))) float floatx4;

// ---------------------------------------------------------------------------
// fp32 -> bf16 RNE pack, 2 floats -> 1 u32. Pure integer SSA — no union, so
// no scratch round-trip (theory: the old union pack blocked SROA -> localMem).
// ---------------------------------------------------------------------------
__device__ __forceinline__ unsigned pack_bf16x2(float lo, float hi) {
    unsigned ul = __float_as_uint(lo);
    unsigned uh = __float_as_uint(hi);
    ul = (ul + 0x7FFFu + ((ul >> 16) & 1u)) >> 16;            // RNE, low half
    uh = (uh + 0x7FFFu + ((uh >> 16) & 1u)) & 0xFFFF0000u;    // RNE, high half
    return (ul & 0xFFFFu) | uh;
}

// Fused x+w fp32->bf16 cast. 8 floats in (32 B), 8 bf16 out (one uint4 store).
__global__ __launch_bounds__(256) void cast2_f32_bf16_kernel(
        const float* __restrict__ x, const float* __restrict__ w,
        uint4* __restrict__ a16, uint4* __restrict__ b16,
        long nx, long nw) {
    const long xc = nx >> 3;
    const long total = (nx + nw) >> 3;
    long c = (long)blockIdx.x * 256 + threadIdx.x;
    const long stride = (long)gridDim.x * 256;
    for (; c < total; c += stride) {
        const float4* src;
        uint4* dst;
        if (c < xc) { src = (const float4*)x + (c << 1); dst = a16 + c; }
        else { const long d = c - xc; src = (const float4*)w + (d << 1); dst = b16 + d; }
        const float4 a = src[0];
        const float4 b = src[1];
        uint4 o;
        o.x = pack_bf16x2(a.x, a.y);
        o.y = pack_bf16x2(a.z, a.w);
        o.z = pack_bf16x2(b.x, b.y);
        o.w = pack_bf16x2(b.z, b.w);
        *dst = o;
    }
}

// ---------------------------------------------------------------------------
// bf16 GEMM, C = A * B^T. 256x256 tile / 512 threads (8 waves 2Mx4N),
// counted-vmcnt 4-phase-per-K-tile schedule (T2+T3/T4+T5+T1 port).
//
// LDS: ring of 4 half-tiles per matrix (each 128 rows x 64 halves = 16 KiB),
//   A(k,h) -> slot (2k+h)&3; same for B. Total 128 KiB.
// Swizzle (verified in previous kernel, 0 bank conflicts):
//   physical 16B-block = logical_kblk ^ (row & 7); staged via pre-swizzled
//   per-lane GLOBAL source + linear global_load_lds dest (both-sides rule).
//
// Per K-tile k, 4 phases = C-quadrants (qm,qn) in order (0,0),(0,1),(1,0),(1,1):
//   ph0: stage A(k+1,1)->slot (2k+3)&3 ; LDS-read A-half0 frags + B-half0 frags ; 16 MFMA
//   ph1: stage B(k+1,1)               ; LDS-read B-half1 frags                ; 16 MFMA
//   ph2: stage A(k+2,0)->slot (2k)&3  ; LDS-read A-half1 frags (B0 in regs)   ; 16 MFMA
//   ph3: stage B(k+2,0)               ; (all operands in regs)                ; 16 MFMA
// Each phase ends: s_waitcnt vmcnt(6) ; s_barrier ; sched_barrier(0).
// Wait math (verified): every fragment read targets a stage issued >= 4 phases
// earlier (tightest: B(k,1), slack 4); vmcnt(6) leaves only the 3 newest
// stages (6 loads) in flight -> all needed data landed. Barrier after each
// wave's own vmcnt makes the guarantee cross-wave. Write-after-read: each
// slot's last LDS read is >= 1 barrier before its restage. Loads are never
// drained to 0 in the main loop (T4) — only once before the last 2 tiles.
// ---------------------------------------------------------------------------
__global__ __launch_bounds__(512, 2) void gemm_bf16_bt(
        const unsigned short* __restrict__ A,
        const unsigned short* __restrict__ B,
        float* __restrict__ C, int M) {
    __shared__ unsigned short sAb[4 * 128 * 64];   // 64 KiB: 4 half-tile slots
    __shared__ unsigned short sBb[4 * 128 * 64];   // 64 KiB

    const int tid  = threadIdx.x;
    const int lane = tid & 63;
    const int wave = tid >> 6;        // 0..7
    const int wqm  = wave >> 2;       // 0..1: M-half of wave within a C-quadrant
    const int wqn  = wave & 3;        // 0..3: N-quarter of wave within a C-quadrant
    const int quad = lane >> 4;       // 0..3
    const int l16  = lane & 15;

    // XCD-aware swizzle (bijective: nwg % 8 == 0 by construction)
    const int nbn = N_DIM / BN;       // 16
    int wg = blockIdx.x;
    const int cpx = gridDim.x >> 3;
    wg = (wg & 7) * cpx + (wg >> 3);
    const int bm = wg / nbn;
    const int bn = wg % nbn;

    // staging map: per stage (one 128x64 half-tile), 2 issues/thread.
    // issue j, wave w: rows j*64 + w*8 + (lane>>3); lane writes LDS phys blk
    // (lane&7) of that row, so source logical kblk = (lane&7) ^ ((lane>>3)&7).
    const int srow     = wave * 8 + (lane >> 3);
    const int kblk_src = (lane & 7) ^ ((lane >> 3) & 7);

    const unsigned short* ag = A + ((size_t)bm * BM + srow) * K_DIM + kblk_src * 8;
    const unsigned short* bg = B + ((size_t)bn * BN + srow) * K_DIM + kblk_src * 8;

#define STAGE(gptr, sptr, slot, half, kt)                                        \
    do {                                                                         \
        _Pragma("unroll")                                                        \
        for (int j_ = 0; j_ < 2; ++j_)                                           \
            __builtin_amdgcn_global_load_lds(                                    \
                (const __attribute__((address_space(1))) void*)(                 \
                    (gptr) + (size_t)((half) * 128 + j_ * 64) * K_DIM            \
                           + (size_t)(kt) * BK),                                 \
                (__attribute__((address_space(3))) void*)(                       \
                    (sptr) + (slot) * 8192 + (j_ * 64 + wave * 8) * BK),         \
                16, 0, 0);                                                       \
    } while (0)

    floatx4 acc[2][2][4][2];
#pragma unroll
    for (int a = 0; a < 2; ++a)
#pragma unroll
        for (int b = 0; b < 2; ++b)
#pragma unroll
            for (int c = 0; c < 4; ++c)
#pragma unroll
                for (int d = 0; d < 2; ++d)
                    acc[a][b][c][d] = (floatx4)0.0f;

    short8 af[4][2];        // A frags for current qm (reused across 2 phases)
    short8 bf0[2][2];       // B frags qn=0 (live whole tile)
    short8 bf1[2][2];       // B frags qn=1

    // frag reads (swizzled, conflict-free: row&7 == l16&7 everywhere)
#define LDA(slot)                                                                \
    do {                                                                         \
        _Pragma("unroll")                                                        \
        for (int mt_ = 0; mt_ < 4; ++mt_)                                        \
        _Pragma("unroll")                                                        \
        for (int ks_ = 0; ks_ < 2; ++ks_)                                        \
            af[mt_][ks_] = *(const short8*)(sAb + (slot) * 8192 +                \
                (wqm * 64 + mt_ * 16 + l16) * BK +                               \
                ((((ks_ << 2) | quad) ^ (l16 & 7)) << 3));                       \
    } while (0)

#define LDB(dst, slot)                                                           \
    do {                                                                         \
        _Pragma("unroll")                                                        \
        for (int nt_ = 0; nt_ < 2; ++nt_)                                        \
        _Pragma("unroll")                                                        \
        for (int ks_ = 0; ks_ < 2; ++ks_)                                        \
            dst[nt_][ks_] = *(const short8*)(sBb + (slot) * 8192 +               \
                (wqn * 32 + nt_ * 16 + l16) * BK +                               \
                ((((ks_ << 2) | quad) ^ (l16 & 7)) << 3));                       \
    } while (0)

#define MMA(qm, qn, bfv)                                                         \
    do {                                                                         \
        __builtin_amdgcn_s_setprio(1);                                           \
        _Pragma("unroll")                                                        \
        for (int mt_ = 0; mt_ < 4; ++mt_)                                        \
        _Pragma("unroll")                                                        \
        for (int nt_ = 0; nt_ < 2; ++nt_)                                        \
        _Pragma("unroll")                                                        \
        for (int ks_ = 0; ks_ < 2; ++ks_)                                        \
            acc[qm][qn][mt_][nt_] = __builtin_amdgcn_mfma_f32_16x16x32_bf16(     \
                af[mt_][ks_], bfv[nt_][ks_], acc[qm][qn][mt_][nt_], 0, 0, 0);    \
        __builtin_amdgcn_s_setprio(0);                                           \
    } while (0)

#define ENDPHASE(n)                                                              \
    do {                                                                         \
        asm volatile("s_waitcnt vmcnt(" #n ")" ::: "memory");                    \
        __builtin_amdgcn_s_barrier();                                            \
        __builtin_amdgcn_sched_barrier(0);                                       \
    } while (0)

    // P0 = (k&1)*2 (compile-time via 2x loop unroll)
#define TILE(P0, k)                                                              \
    do {                                                                         \
        STAGE(ag, sAb, ((P0) ^ 2) + 1, 1, (k) + 1);  /* A(k+1,1) */              \
        LDA((P0));                                                               \
        LDB(bf0, (P0));                                                          \
        MMA(0, 0, bf0);                                                          \
        ENDPHASE(6);                                                             \
        STAGE(bg, sBb, ((P0) ^ 2) + 1, 1, (k) + 1);  /* B(k+1,1) */              \
        LDB(bf1, (P0) + 1);                                                      \
        MMA(0, 1, bf1);                                                          \
        ENDPHASE(6);                                                             \
        STAGE(ag, sAb, (P0), 0, (k) + 2);            /* A(k+2,0) */              \
        LDA((P0) + 1);                                                           \
        MMA(1, 0, bf0);                                                          \
        ENDPHASE(6);                                                             \
        STAGE(bg, sBb, (P0), 0, (k) + 2);            /* B(k+2,0) */              \
        MMA(1, 1, bf1);                                                          \
        ENDPHASE(6);                                                             \
    } while (0)

#define TILE_NOSYNC(P0)                                                          \
    do {                                                                         \
        LDA((P0));     LDB(bf0, (P0)); MMA(0, 0, bf0);                           \
        LDB(bf1, (P0) + 1);            MMA(0, 1, bf1);                           \
        LDA((P0) + 1);                 MMA(1, 0, bf0);                           \
                                       MMA(1, 1, bf1);                           \
    } while (0)

    // ---- prologue: A(0,0)->0 B(0,0)->0 A(0,1)->1 B(0,1)->1 A(1,0)->2 B(1,0)->2
    STAGE(ag, sAb, 0, 0, 0);
    STAGE(bg, sBb, 0, 0, 0);
    STAGE(ag, sAb, 1, 1, 0);
    STAGE(bg, sBb, 1, 1, 0);
    STAGE(ag, sAb, 2, 0, 1);
    STAGE(bg, sBb, 2, 0, 1);
    // first 2 stages (A(0,0),B(0,0)) must land; allow newest 4 stages in flight
    asm volatile("s_waitcnt vmcnt(8)" ::: "memory");
    __builtin_amdgcn_s_barrier();
    __builtin_amdgcn_sched_barrier(0);

    // ---- main loop: tiles 0..NT-3 (stage targets k+1 <= NT-2, k+2 <= NT-1) ----
#pragma unroll 1
    for (int k = 0; k < NT - 2; k += 2) {
        TILE(0, k);
        TILE(2, k + 1);
    }

    // ---- epilogue: issue last 2 half-tiles, drain once, run tiles 62/63 ----
    STAGE(ag, sAb, 3, 1, NT - 1);   // A(63,1) -> slot 3
    STAGE(bg, sBb, 3, 1, NT - 1);   // B(63,1) -> slot 3
    asm volatile("s_waitcnt vmcnt(0)" ::: "memory");
    __builtin_amdgcn_s_barrier();
    __builtin_amdgcn_sched_barrier(0);
    TILE_NOSYNC(0);                 // tile NT-2: slots 0/1
    TILE_NOSYNC(2);                 // tile NT-1: slots 2/3

    // ---- C write: C/D layout col = lane&15, row = quad*4 + reg (m89-verified)
#pragma unroll
    for (int qm = 0; qm < 2; ++qm)
#pragma unroll
        for (int qn = 0; qn < 2; ++qn)
#pragma unroll
            for (int mt = 0; mt < 4; ++mt)
#pragma unroll
                for (int nt = 0; nt < 2; ++nt) {
                    const int col = bn * BN + qn * 128 + wqn * 32 + nt * 16 + l16;
                    const size_t row0 = (size_t)bm * BM + qm * 128 + wqm * 64
                                      + mt * 16 + quad * 4;
#pragma unroll
                    for (int r = 0; r < 4; ++r)
                        C[(row0 + r) * N_DIM + col] = acc[qm][qn][mt][nt][r];
                }
}

// Correctness fallback if ws too small / M not a tile multiple (fp32 vector ALU).
__global__ __launch_bounds__(256) void gemm_naive_f32(
        const float* __restrict__ X, const float* __restrict__ W,
        float* __restrict__ C, long total) {
    long idx = (long)blockIdx.x * 256 + threadIdx.x;
    if (idx >= total) return;
    const long row = idx / N_DIM, col = idx % N_DIM;
    const float* x = X + row * K_DIM;
    const float* w = W + col * K_DIM;
    float s = 0.f;
    for (int k = 0; k < K_DIM; k += 4) {
        floatx4 a = *(const floatx4*)(x + k);
        floatx4 b = *(const floatx4*)(w + k);
        s += a[0] * b[0] + a[1] * b[1] + a[2] * b[2] + a[3] * b[3];
    }
    C[idx] = s;
}

extern "C" void kernel_launch(void* const* d_in, const int* in_sizes, int n_in,
                              void* d_out, int out_size, void* d_ws, size_t ws_size,
                              hipStream_t stream) {
    const float* x = (const float*)d_in[0];   // (4,2048,4096) fp32
    const float* w = (const float*)d_in[1];   // (4096,4096) fp32, (N,K) = B^T layout
    float* out = (float*)d_out;               // (M, 4096) fp32

    const long nx = (long)in_sizes[0];        // M*K
    const long nw = (long)in_sizes[1];        // N*K
    const int  M  = (int)(nx / K_DIM);        // 8192

    const size_t a_bytes = (size_t)nx * 2;    // 64 MiB
    const size_t b_bytes = (size_t)nw * 2;    // 32 MiB

    if (ws_size >= a_bytes + b_bytes && (M % BM) == 0) {
        unsigned short* a16 = (unsigned short*)d_ws;
        unsigned short* b16 = (unsigned short*)((char*)d_ws + a_bytes);
        cast2_f32_bf16_kernel<<<4096, 256, 0, stream>>>(
            x, w, (uint4*)a16, (uint4*)b16, nx, nw);
        const int nwg = (M / BM) * (N_DIM / BN);   // 32*16 = 512, %8 == 0
        gemm_bf16_bt<<<dim3(nwg), 512, 0, stream>>>(a16, b16, out, M);
    } else {
        const long total = (long)M * N_DIM;
        gemm_naive_f32<<<(int)((total + 255) / 256), 256, 0, stream>>>(x, w, out, total);
    }
}